// Round 8
// baseline (1957.581 us; speedup 1.0000x reference)
//
#include <hip/hip_runtime.h>

#define T_TOK 8192
#define DDIM  2048
#define NEXP  8
#define IDIM  1408
#define SIDIM 2816
#define MAXSLOTS 18432  // 16384 + 8*256 worst-case padding (256-aligned)

typedef short  v8s  __attribute__((ext_vector_type(8)));
typedef __bf16 v8bf __attribute__((ext_vector_type(8)));
typedef float  v4f  __attribute__((ext_vector_type(4)));

__device__ __forceinline__ unsigned short f2bf_bits(float f){
  union { float fv; unsigned u; } v; v.fv = f;
  unsigned r = v.u + 0x7fffu + ((v.u >> 16) & 1u);  // RNE
  return (unsigned short)(r >> 16);
}

__device__ __forceinline__ void gld16(const void* g, void* l){
  __builtin_amdgcn_global_load_lds(
      (const __attribute__((address_space(1))) unsigned int*)g,
      (__attribute__((address_space(3))) unsigned int*)l, 16, 0, 0);
}

__device__ __forceinline__ v4f mfma16(v8s a, v8s b, v4f c){
  return __builtin_amdgcn_mfma_f32_16x16x32_bf16(
      __builtin_bit_cast(v8bf, a), __builtin_bit_cast(v8bf, b), c, 0, 0, 0);
}

// XCD-chunked bijective swizzle (m204) + GROUP-8 row-band raster (R1-proven).
__device__ __forceinline__ int2 raster(int bid, int nx, int ny){
  int nwg = nx * ny;
  int xcd = bid & 7;
  int q = nwg >> 3, r = nwg & 7;
  int lid = (xcd < r ? xcd*(q+1) : r*(q+1) + (xcd-r)*q) + (bid >> 3);
  const int G = 8;
  int band  = lid / (G*ny);
  int first = band * G;
  int gsz   = (nx - first) < G ? (nx - first) : G;
  int rem   = lid - band*G*ny;
  int pm = first + rem % gsz;
  int pn = rem / gsz;
  return make_int2(pm, pn);
}

#define BAR() __builtin_amdgcn_s_barrier()
#define LGKM0() do{ asm volatile("s_waitcnt lgkmcnt(0)":::"memory"); \
                    __builtin_amdgcn_sched_barrier(0); }while(0)

// ---------------- small kernels ----------------

__global__ __launch_bounds__(256) void route_init_k(int* rows, float* roww, int* counts){
  int i = blockIdx.x*256 + threadIdx.x;
  if (i < MAXSLOTS){ rows[i] = 0; roww[i] = 0.f; }
  if (i < NEXP) counts[i] = 0;
}

__global__ __launch_bounds__(256) void cvt_bf16_k(const float4* __restrict__ s,
                                                  ushort4* __restrict__ d, int n4){
  int i = blockIdx.x*256 + threadIdx.x;
  int stride = gridDim.x*256;
  for (; i < n4; i += stride){
    float4 v = s[i];
    d[i] = make_ushort4(f2bf_bits(v.x), f2bf_bits(v.y), f2bf_bits(v.z), f2bf_bits(v.w));
  }
}

// Interleave-concat convert: dest row 2i <- m1[i], row 2i+1 <- m3[i] (per expert).
__global__ __launch_bounds__(256) void cvt_pair_k(const float4* __restrict__ m1,
    const float4* __restrict__ m3, ushort4* __restrict__ d,
    int I, int k4, long long n4){
  long long i = (long long)blockIdx.x*256 + threadIdx.x;
  long long stride = (long long)gridDim.x*256;
  for (; i < n4; i += stride){
    long long per_mat = (long long)2*I*k4;
    int e = (int)(i / per_mat);
    long long rem = i - (long long)e*per_mat;
    int r = (int)(rem / k4);
    int k = (int)(rem - (long long)r*k4);
    const float4* src = (r & 1) ? m3 : m1;
    float4 v = src[((long long)e*I + (r>>1))*k4 + k];
    d[i] = make_ushort4(f2bf_bits(v.x), f2bf_bits(v.y), f2bf_bits(v.z), f2bf_bits(v.w));
  }
}

// gate (fp32) + x -> bf16 cast. One wave per token.
__global__ __launch_bounds__(256) void gate_cast_k(const float* __restrict__ x,
    const float* __restrict__ gw, unsigned short* __restrict__ xbf,
    int* __restrict__ tidx, float* __restrict__ tw, int* __restrict__ counts){
  int t = threadIdx.x, w = t>>6, lane = t&63;
  int token = blockIdx.x*4 + w;
  const float* xr = x + (size_t)token*DDIM;
  float acc[NEXP];
  #pragma unroll
  for (int e=0;e<NEXP;++e) acc[e]=0.f;
  #pragma unroll
  for (int i=0;i<8;++i){
    int d = i*256 + lane*4;
    float4 xv = *(const float4*)(xr + d);
    *(ushort4*)(xbf + (size_t)token*DDIM + d) =
        make_ushort4(f2bf_bits(xv.x), f2bf_bits(xv.y), f2bf_bits(xv.z), f2bf_bits(xv.w));
    #pragma unroll
    for (int e=0;e<NEXP;++e){
      float4 g = *(const float4*)(gw + e*DDIM + d);
      acc[e] += xv.x*g.x + xv.y*g.y + xv.z*g.z + xv.w*g.w;
    }
  }
  #pragma unroll
  for (int off=32; off; off>>=1){
    #pragma unroll
    for (int e=0;e<NEXP;++e) acc[e] += __shfl_xor(acc[e], off);
  }
  if (lane == 0){
    float mx = acc[0];
    #pragma unroll
    for (int e=1;e<NEXP;++e) mx = fmaxf(mx, acc[e]);
    float p[NEXP], s = 0.f;
    #pragma unroll
    for (int e=0;e<NEXP;++e){ p[e] = __expf(acc[e]-mx); s += p[e]; }
    float inv = 1.f/s;
    #pragma unroll
    for (int e=0;e<NEXP;++e) p[e] *= inv;
    int i0 = 0;
    #pragma unroll
    for (int e=1;e<NEXP;++e) if (p[e] > p[i0]) i0 = e;
    int i1 = (i0==0) ? 1 : 0;
    #pragma unroll
    for (int e=0;e<NEXP;++e) if (e!=i0 && e!=i1 && p[e] > p[i1]) i1 = e;
    tidx[token*2+0] = i0; tidx[token*2+1] = i1;
    tw[token*2+0] = p[i0]; tw[token*2+1] = p[i1];
    atomicAdd(&counts[i0], 1); atomicAdd(&counts[i1], 1);
  }
}

__global__ void route_offsets_k(const int* counts, int* pad_off, int* pad_cnt, int* fill){
  if (threadIdx.x == 0){
    int o = 0;
    for (int e=0;e<NEXP;++e){
      pad_off[e] = o;
      int pc = (counts[e] + 255) & ~255;   // 256-aligned for BM=256
      pad_cnt[e] = pc;
      o += pc;
    }
  }
  if (threadIdx.x < NEXP) fill[threadIdx.x] = 0;
}

__global__ __launch_bounds__(256) void scatter_k(const int* __restrict__ tidx,
    const float* __restrict__ tw, const int* __restrict__ pad_off,
    int* __restrict__ fill, int* __restrict__ rows, float* __restrict__ roww){
  int t = blockIdx.x*256 + threadIdx.x;
  int lane = threadIdx.x & 63;
  #pragma unroll
  for (int k=0;k<2;++k){
    int e = tidx[t*2+k];
    float wgt = tw[t*2+k];
    for (int ee=0; ee<NEXP; ++ee){
      unsigned long long m = __ballot(e == ee);
      if (m){
        int leader = __ffsll((unsigned long long)m) - 1;
        int base = 0;
        if (lane == leader) base = atomicAdd(&fill[ee], __popcll(m));
        base = __shfl(base, leader);
        if (e == ee){
          int rank = __popcll(m & ((1ull<<lane)-1ull));
          int pos = pad_off[ee] + base + rank;
          rows[pos] = t; roww[pos] = wgt;
        }
      }
    }
  }
}

// ====== m201-style 8-phase GEMM core ======
// 256x256 tile, 8 waves (2M x 4N), K-tile 64 = 2 kk-blocks of 32.
// LDS: 8 slots of 16KB: slot(par, op, kk) = (par*4 + op*2 + kk), op 0=A 1=B.
// Per K-tile: 4 phases {ds_read | stage 1 half | bar | lgkm0 | 16 MFMA | bar},
// counted vmcnt(6) at tile boundary (stream leads consumption by 7 halves).

// SWIGLU variant: B pair-interleaved (row 2i = w1_i, 2i+1 = w3_i); H bf16 out.
template<bool GATHER>
__global__ __launch_bounds__(512) void gemm8p_swiglu_k(
    const unsigned short* __restrict__ Abase,
    const unsigned short* __restrict__ Bbase,
    unsigned short* __restrict__ Hbase,
    const int* __restrict__ rows,
    const int* __restrict__ pad_off, const int* __restrict__ pad_cnt,
    int K, int N, int ny)
{
  int e = blockIdx.z;
  int off = 0, mcnt = T_TOK;
  if (GATHER){ off = pad_off[e]; mcnt = pad_cnt[e]; }
  int2 pmn = raster(blockIdx.x, T_TOK/256, ny);
  int brow = pmn.x * 256;
  if (brow >= mcnt) return;
  int bcol = pmn.y * 256;

  const unsigned short* Bm = Bbase + (size_t)e * (size_t)N * (size_t)K;
  unsigned short* H = Hbase + (size_t)off * (size_t)(N>>1);

  __shared__ unsigned short lds[8*8192];

  int t = threadIdx.x, w = t>>6, lane = t&63;
  const unsigned short *ap[2], *bp[2];
  {
    int scol = (t&3)*8;
    #pragma unroll
    for (int j=0;j<2;++j){
      int r = brow + j*128 + (t>>2);
      int tok = GATHER ? rows[off + r] : r;
      ap[j] = Abase + (size_t)tok*(size_t)K + scol;
      bp[j] = Bm + (size_t)(bcol + j*128 + (t>>2))*(size_t)K + scol;
    }
  }

  auto STG = [&](int par, int op, int kk, int kt){
    const unsigned short* const* sp = op ? bp : ap;
    char* dst = (char*)lds + (size_t)(par*4 + op*2 + kk)*16384;
    #pragma unroll
    for (int j=0;j<2;++j)
      gld16(sp[j] + kt*64 + kk*32, dst + (j*512 + t)*16);
  };

  v4f acc[8][4];
  #pragma unroll
  for (int m=0;m<8;++m)
    #pragma unroll
    for (int n=0;n<4;++n) acc[m][n] = (v4f){0.f,0.f,0.f,0.f};

  int fr = lane & 15, fq = lane >> 4;
  int wm = w >> 2, wn = w & 3;   // wave tile: rows wm*128, cols wn*64

  v8s af[8], bf[2];
  auto RDA = [&](int par, int kk){
    const unsigned short* sb = lds + (par*4 + kk)*8192;
    #pragma unroll
    for (int m=0;m<8;++m) af[m] = *(const v8s*)(sb + (wm*128 + m*16 + fr)*32 + fq*8);
  };
  auto RDB = [&](int par, int kk, int np){
    const unsigned short* sb = lds + (par*4 + 2 + kk)*8192;
    #pragma unroll
    for (int n2=0;n2<2;++n2) bf[n2] = *(const v8s*)(sb + (wn*64 + (np*2+n2)*16 + fr)*32 + fq*8);
  };
  auto MM0 = [&](){
    __builtin_amdgcn_s_setprio(1);
    #pragma unroll
    for (int n2=0;n2<2;++n2)
      #pragma unroll
      for (int m=0;m<8;++m) acc[m][n2] = mfma16(af[m], bf[n2], acc[m][n2]);
    __builtin_amdgcn_s_setprio(0);
  };
  auto MM1 = [&](){
    __builtin_amdgcn_s_setprio(1);
    #pragma unroll
    for (int n2=0;n2<2;++n2)
      #pragma unroll
      for (int m=0;m<8;++m) acc[m][2+n2] = mfma16(af[m], bf[n2], acc[m][2+n2]);
    __builtin_amdgcn_s_setprio(0);
  };

  int NT = K/64;
  // prologue: t0 {A0,B0,A1,B1} + t1 {A0,B0,A1}
  STG(0,0,0,0); STG(0,1,0,0); STG(0,0,1,0); STG(0,1,1,0);
  if (NT > 1){ STG(1,0,0,1); STG(1,1,0,1); STG(1,0,1,1); }
  if (NT > 1) asm volatile("s_waitcnt vmcnt(6)":::"memory");
  else        asm volatile("s_waitcnt vmcnt(0)":::"memory");
  __builtin_amdgcn_sched_barrier(0);
  BAR();

  for (int tt=0; tt<NT; ++tt){
    int par = tt & 1, po = par ^ 1;
    // q0: A kk0 + B kk0 pair0 | stage (t+1) B kk1
    RDA(par,0); RDB(par,0,0);
    if (tt+1 < NT) STG(po,1,1,tt+1);
    BAR(); LGKM0(); MM0(); BAR();
    // q1: B kk0 pair1 | stage (t+2) A kk0
    RDB(par,0,1);
    if (tt+2 < NT) STG(par,0,0,tt+2);
    BAR(); LGKM0(); MM1(); BAR();
    // q2: A kk1 + B kk1 pair0 | stage (t+2) B kk0
    RDA(par,1); RDB(par,1,0);
    if (tt+2 < NT) STG(par,1,0,tt+2);
    BAR(); LGKM0(); MM0(); BAR();
    // q3: B kk1 pair1 | stage (t+2) A kk1 | tile-boundary counted wait
    RDB(par,1,1);
    if (tt+2 < NT) STG(par,0,1,tt+2);
    BAR(); LGKM0(); MM1();
    if (tt+1 < NT){
      if (tt+1 == NT-1) asm volatile("s_waitcnt vmcnt(0)":::"memory");
      else              asm volatile("s_waitcnt vmcnt(6)":::"memory");
      __builtin_amdgcn_sched_barrier(0);
    }
    BAR();
  }

  // swiglu pair epilogue: col 2i = silu-arg (w1 row i), col 2i+1 = w3 row i.
  int hld = N >> 1;
  #pragma unroll
  for (int m=0;m<8;++m){
    #pragma unroll
    for (int n=0;n<4;++n){
      #pragma unroll
      for (int j=0;j<4;++j){
        float v = acc[m][n][j];
        float pv = __shfl_xor(v, 1);   // partner column (lane^1 flips fr bit0)
        if (!(fr & 1)){
          float a = v, b = pv;
          float h = a * b / (1.f + __expf(-a));
          int row = brow + wm*128 + m*16 + fq*4 + j;
          int hcol = (bcol>>1) + wn*32 + n*8 + (fr>>1);
          H[(size_t)row*(size_t)hld + hcol] = f2bf_bits(h);
        }
      }
    }
  }
}

// OUT variant: out = A@B^T (N = DDIM). ATOMIC: out[tok] += w*val; else store.
template<bool ATOMIC>
__global__ __launch_bounds__(512) void gemm8p_out_k(
    const unsigned short* __restrict__ Abase,
    const unsigned short* __restrict__ Bbase,
    float* __restrict__ out,
    const int* __restrict__ rows, const float* __restrict__ roww,
    const int* __restrict__ pad_off, const int* __restrict__ pad_cnt,
    int K)
{
  int e = blockIdx.z;
  int off = 0, mcnt = T_TOK;
  if (ATOMIC){ off = pad_off[e]; mcnt = pad_cnt[e]; }
  int2 pmn = raster(blockIdx.x, T_TOK/256, DDIM/256);
  int brow = pmn.x * 256;
  if (brow >= mcnt) return;
  int bcol = pmn.y * 256;

  const unsigned short* A  = Abase + (size_t)off * (size_t)K;
  const unsigned short* Bm = Bbase + (size_t)e * (size_t)DDIM * (size_t)K;

  __shared__ unsigned short lds[8*8192];

  int t = threadIdx.x, w = t>>6, lane = t&63;
  const unsigned short *ap[2], *bp[2];
  {
    int scol = (t&3)*8;
    #pragma unroll
    for (int j=0;j<2;++j){
      ap[j] = A  + (size_t)(brow + j*128 + (t>>2))*(size_t)K + scol;
      bp[j] = Bm + (size_t)(bcol + j*128 + (t>>2))*(size_t)K + scol;
    }
  }

  auto STG = [&](int par, int op, int kk, int kt){
    const unsigned short* const* sp = op ? bp : ap;
    char* dst = (char*)lds + (size_t)(par*4 + op*2 + kk)*16384;
    #pragma unroll
    for (int j=0;j<2;++j)
      gld16(sp[j] + kt*64 + kk*32, dst + (j*512 + t)*16);
  };

  v4f acc[8][4];
  #pragma unroll
  for (int m=0;m<8;++m)
    #pragma unroll
    for (int n=0;n<4;++n) acc[m][n] = (v4f){0.f,0.f,0.f,0.f};

  int fr = lane & 15, fq = lane >> 4;
  int wm = w >> 2, wn = w & 3;

  v8s af[8], bf[2];
  auto RDA = [&](int par, int kk){
    const unsigned short* sb = lds + (par*4 + kk)*8192;
    #pragma unroll
    for (int m=0;m<8;++m) af[m] = *(const v8s*)(sb + (wm*128 + m*16 + fr)*32 + fq*8);
  };
  auto RDB = [&](int par, int kk, int np){
    const unsigned short* sb = lds + (par*4 + 2 + kk)*8192;
    #pragma unroll
    for (int n2=0;n2<2;++n2) bf[n2] = *(const v8s*)(sb + (wn*64 + (np*2+n2)*16 + fr)*32 + fq*8);
  };
  auto MM0 = [&](){
    __builtin_amdgcn_s_setprio(1);
    #pragma unroll
    for (int n2=0;n2<2;++n2)
      #pragma unroll
      for (int m=0;m<8;++m) acc[m][n2] = mfma16(af[m], bf[n2], acc[m][n2]);
    __builtin_amdgcn_s_setprio(0);
  };
  auto MM1 = [&](){
    __builtin_amdgcn_s_setprio(1);
    #pragma unroll
    for (int n2=0;n2<2;++n2)
      #pragma unroll
      for (int m=0;m<8;++m) acc[m][2+n2] = mfma16(af[m], bf[n2], acc[m][2+n2]);
    __builtin_amdgcn_s_setprio(0);
  };

  int NT = K/64;
  STG(0,0,0,0); STG(0,1,0,0); STG(0,0,1,0); STG(0,1,1,0);
  if (NT > 1){ STG(1,0,0,1); STG(1,1,0,1); STG(1,0,1,1); }
  if (NT > 1) asm volatile("s_waitcnt vmcnt(6)":::"memory");
  else        asm volatile("s_waitcnt vmcnt(0)":::"memory");
  __builtin_amdgcn_sched_barrier(0);
  BAR();

  for (int tt=0; tt<NT; ++tt){
    int par = tt & 1, po = par ^ 1;
    RDA(par,0); RDB(par,0,0);
    if (tt+1 < NT) STG(po,1,1,tt+1);
    BAR(); LGKM0(); MM0(); BAR();
    RDB(par,0,1);
    if (tt+2 < NT) STG(par,0,0,tt+2);
    BAR(); LGKM0(); MM1(); BAR();
    RDA(par,1); RDB(par,1,0);
    if (tt+2 < NT) STG(par,1,0,tt+2);
    BAR(); LGKM0(); MM0(); BAR();
    RDB(par,1,1);
    if (tt+2 < NT) STG(par,0,1,tt+2);
    BAR(); LGKM0(); MM1();
    if (tt+1 < NT){
      if (tt+1 == NT-1) asm volatile("s_waitcnt vmcnt(0)":::"memory");
      else              asm volatile("s_waitcnt vmcnt(6)":::"memory");
      __builtin_amdgcn_sched_barrier(0);
    }
    BAR();
  }

  #pragma unroll
  for (int m=0;m<8;++m){
    #pragma unroll
    for (int r=0;r<4;++r){
      int slot = brow + wm*128 + m*16 + fq*4 + r;
      int tok = slot; float wgt = 1.f;
      if (ATOMIC){ tok = rows[off+slot]; wgt = roww[off+slot]; }
      #pragma unroll
      for (int n=0;n<4;++n){
        int col = bcol + wn*64 + n*16 + fr;
        float v = acc[m][n][r];
        if (ATOMIC) atomicAdd(out + (size_t)tok*DDIM + col, wgt*v);
        else        out[(size_t)slot*DDIM + col] = v;
      }
    }
  }
}

// ---------------- launcher ----------------

extern "C" void kernel_launch(void* const* d_in, const int* in_sizes, int n_in,
                              void* d_out, int out_size, void* d_ws, size_t ws_size,
                              hipStream_t stream)
{
  const float* x   = (const float*)d_in[0];
  const float* gw  = (const float*)d_in[1];
  const float* w1  = (const float*)d_in[2];
  const float* w2  = (const float*)d_in[3];
  const float* w3  = (const float*)d_in[4];
  const float* sw1 = (const float*)d_in[5];
  const float* sw2 = (const float*)d_in[6];
  const float* sw3 = (const float*)d_in[7];
  float* out = (float*)d_out;

  char* p = (char*)d_ws;
  auto alloc = [&](size_t bytes)->char*{
    char* r = p; p += (bytes + 255) & ~(size_t)255; return r;
  };

  unsigned short* xbf  = (unsigned short*)alloc((size_t)T_TOK*DDIM*2);
  unsigned short* wcat = (unsigned short*)alloc((size_t)NEXP*2*IDIM*DDIM*2);
  unsigned short* scat = (unsigned short*)alloc((size_t)2*SIDIM*DDIM*2);
  unsigned short* w2b  = (unsigned short*)alloc((size_t)NEXP*DDIM*IDIM*2);
  unsigned short* sw2b = (unsigned short*)alloc((size_t)DDIM*SIDIM*2);
  unsigned short* Hbuf = (unsigned short*)alloc((size_t)MAXSLOTS*IDIM*2);
  int*   tidx    = (int*)  alloc((size_t)T_TOK*2*4);
  float* tw      = (float*)alloc((size_t)T_TOK*2*4);
  int*   rows    = (int*)  alloc((size_t)MAXSLOTS*4);
  float* roww    = (float*)alloc((size_t)MAXSLOTS*4);
  int*   counts  = (int*)  alloc(NEXP*4);
  int*   pad_off = (int*)  alloc(NEXP*4);
  int*   pad_cnt = (int*)  alloc(NEXP*4);
  int*   fill    = (int*)  alloc(NEXP*4);

  route_init_k<<<(MAXSLOTS+255)/256, 256, 0, stream>>>(rows, roww, counts);

  cvt_pair_k<<<2048, 256, 0, stream>>>((const float4*)w1, (const float4*)w3,
      (ushort4*)wcat, IDIM, DDIM/4, (long long)NEXP*2*IDIM*(DDIM/4));
  cvt_pair_k<<<1024, 256, 0, stream>>>((const float4*)sw1, (const float4*)sw3,
      (ushort4*)scat, SIDIM, DDIM/4, (long long)2*SIDIM*(DDIM/4));
  cvt_bf16_k<<<2048, 256, 0, stream>>>((const float4*)w2,  (ushort4*)w2b,
      (int)((size_t)NEXP*DDIM*IDIM/4));
  cvt_bf16_k<<<1024, 256, 0, stream>>>((const float4*)sw2, (ushort4*)sw2b,
      (int)((size_t)DDIM*SIDIM/4));

  gate_cast_k<<<T_TOK/4, 256, 0, stream>>>(x, gw, xbf, tidx, tw, counts);

  route_offsets_k<<<1, 64, 0, stream>>>(counts, pad_off, pad_cnt, fill);
  scatter_k<<<T_TOK/256, 256, 0, stream>>>(tidx, tw, pad_off, fill, rows, roww);

  // shared expert
  gemm8p_swiglu_k<false><<<dim3((T_TOK/256)*(2*SIDIM/256), 1, 1), 512, 0, stream>>>(
      xbf, scat, Hbuf, nullptr, nullptr, nullptr, DDIM, 2*SIDIM, 2*SIDIM/256);
  gemm8p_out_k<false><<<dim3((T_TOK/256)*(DDIM/256), 1, 1), 512, 0, stream>>>(
      Hbuf, sw2b, out, nullptr, nullptr, nullptr, nullptr, SIDIM);

  // routed experts
  gemm8p_swiglu_k<true><<<dim3((T_TOK/256)*(2*IDIM/256), 1, NEXP), 512, 0, stream>>>(
      xbf, wcat, Hbuf, rows, pad_off, pad_cnt, DDIM, 2*IDIM, 2*IDIM/256);
  gemm8p_out_k<true><<<dim3((T_TOK/256)*(DDIM/256), 1, NEXP), 512, 0, stream>>>(
      Hbuf, w2b, out, rows, roww, pad_off, pad_cnt, IDIM);
}